// Round 15
// baseline (152.580 us; speedup 1.0000x reference)
//
#include <hip/hip_runtime.h>
#include <math.h>

typedef unsigned int u32;
typedef unsigned long long u64;
typedef unsigned short u16;
typedef __attribute__((ext_vector_type(8))) short bf16x8;
typedef __attribute__((ext_vector_type(4))) float f32x4;

#define NHEADS 8
#define HH 24
#define WW 24
#define HW 576
#define CS 256        // channels per group
#define CHD 32        // channels per head
#define NN 2304       // HW * NGROUPS
#define NGROUPS 4
#define TOPK 1843     // int(2304 * 0.8)
#define DIM 1024
#define EPSN 1e-12f

__device__ __forceinline__ u32 fkey(float f) {
    u32 u = __float_as_uint(f);
    return u ^ ((u >> 31) ? 0xFFFFFFFFu : 0x80000000u);  // monotonic map
}
__device__ __forceinline__ float fkey_inv(u32 k) {
    return __uint_as_float((k & 0x80000000u) ? (k ^ 0x80000000u) : ~k);
}
__device__ __forceinline__ u16 f2bf(float f) {          // RNE fp32->bf16
    u32 u = __float_as_uint(f);
    return (u16)((u + 0x7FFFu + ((u >> 16) & 1u)) >> 16);
}
__device__ __forceinline__ u32 shiftOf128(u32 rg) {     // 128-bin shift
    return (rg > 127u) ? (u32)(25 - __clz(rg)) : 0u;
}

// ---------------------------------------------------------------------------
// Kernel 1: fused group-mix (w_qkv) + depthwise 3x3 conv + q/k norm reduce.
// Block c owns channel c's ENTIRE q/k rows -> computes scales in-kernel.
// ---------------------------------------------------------------------------
__global__ __launch_bounds__(256) void qkv_conv_kernel(
    const float* __restrict__ x, const float* __restrict__ w_qkv,
    const float* __restrict__ w_dw,
    float* __restrict__ qb, float* __restrict__ kb, u16* __restrict__ vb16,
    float* __restrict__ scales)
{
    __shared__ float xp[NGROUPS][26][26];
    __shared__ float wq[48];
    __shared__ float wd[108];
    __shared__ float redq[4], redk[4];
    int c = blockIdx.x;          // 0..255
    int tid = threadIdx.x;
    int lane = tid & 63, wid = tid >> 6;

    for (int i = tid; i < NGROUPS * 26 * 26; i += 256) ((float*)xp)[i] = 0.f;
    if (tid < 48) wq[tid] = w_qkv[tid];
    if (tid < 108) wd[tid] = w_dw[tid];
    __syncthreads();
    for (int i = tid; i < NGROUPS * HW; i += 256) {
        int t = i / HW, p = i % HW;
        int hh = p / WW, ww = p % WW;
        xp[t][hh + 1][ww + 1] = x[(size_t)(t * CS + c) * HW + p];
    }
    __syncthreads();

    int hd = c >> 5, ch = c & 31;
    float ssq = 0.f, ssk = 0.f;
    for (int p = tid; p < HW; p += 256) {
        int hh = p / WW, ww = p % WW;
        float res[12];
        #pragma unroll
        for (int s = 0; s < 12; ++s) {
            float acc = 0.f;
            #pragma unroll
            for (int t = 0; t < NGROUPS; ++t) {
                float cv = 0.f;
                #pragma unroll
                for (int dh = 0; dh < 3; ++dh)
                    #pragma unroll
                    for (int dw = 0; dw < 3; ++dw)
                        cv += xp[t][hh + dh][ww + dw] * wd[s * 9 + dh * 3 + dw];
                acc += wq[s * 4 + t] * cv;
            }
            res[s] = acc;
        }
        #pragma unroll
        for (int tt = 0; tt < 4; ++tt) {
            int n = p * 4 + tt;
            size_t off = ((size_t)hd * CHD + ch) * NN + n;
            qb[off] = res[tt];
            kb[off] = res[4 + tt];
            vb16[off] = f2bf(res[8 + tt]);
            ssq += res[tt] * res[tt];
            ssk += res[4 + tt] * res[4 + tt];
        }
    }
    #pragma unroll
    for (int off = 32; off > 0; off >>= 1) {
        ssq += __shfl_down(ssq, off);
        ssk += __shfl_down(ssk, off);
    }
    if (lane == 0) { redq[wid] = ssq; redk[wid] = ssk; }
    __syncthreads();
    if (tid == 0) {
        float sq = redq[0] + redq[1] + redq[2] + redq[3];
        float sk = redk[0] + redk[1] + redk[2] + redk[3];
        scales[c] = 1.f / fmaxf(sqrtf(sq), EPSN);
        scales[256 + c] = 1.f / fmaxf(sqrtf(sk), EPSN);
    }
}

// ---------------------------------------------------------------------------
// Kernel 2b: transpose+scale+cast q,k: [h][c][n] fp32 -> [h][n][c] bf16
// Temperature folded into Qt.
// ---------------------------------------------------------------------------
__global__ __launch_bounds__(256) void transpose_cast_kernel(
    const float* __restrict__ qb, const float* __restrict__ kb,
    const float* __restrict__ scales, const float* __restrict__ temp,
    u16* __restrict__ Qt, u16* __restrict__ Kt)
{
    __shared__ float tile[32][33];
    int ntile = blockIdx.x;        // 0..71
    int h = blockIdx.y;            // 0..7
    int which = blockIdx.z;        // 0=q 1=k
    const float* src = which ? kb : qb;
    const float* scl = scales + which * 256;
    u16* dst = which ? Kt : Qt;
    float tf = which ? 1.f : temp[h];
    int tid = threadIdx.x;
    int n0 = ntile * 32;
    #pragma unroll
    for (int cc = 0; cc < 32; cc += 8) {
        int c = cc + (tid >> 5);
        tile[c][tid & 31] = src[(size_t)(h * CHD + c) * NN + n0 + (tid & 31)]
                            * scl[h * CHD + c] * tf;
    }
    __syncthreads();
    int cgrp = tid & 7, nrow = tid >> 3;
    #pragma unroll
    for (int c0 = 0; c0 < 32; c0 += 16) {
        int c = c0 + cgrp * 2;
        u16 v0 = f2bf(tile[c][nrow]);
        u16 v1 = f2bf(tile[c + 1][nrow]);
        ushort2 v; v.x = v0; v.y = v1;
        *(ushort2*)(dst + ((size_t)h * NN + n0 + nrow) * CHD + c) = v;
    }
}

// ---------------------------------------------------------------------------
// Kernel 2c: cast w_proj fp32 -> bf16
// ---------------------------------------------------------------------------
__global__ __launch_bounds__(256) void cast_wproj_kernel(
    const float* __restrict__ wp, u16* __restrict__ wpb)
{
    int i = blockIdx.x * 256 + threadIdx.x;   // DIM*DIM/4 elems of float4
    float4 v = ((const float4*)wp)[i];
    ushort4 o;
    o.x = f2bf(v.x); o.y = f2bf(v.y); o.z = f2bf(v.z); o.w = f2bf(v.w);
    ((ushort4*)wpb)[i] = o;
}

// ---------------------------------------------------------------------------
// Kernel 3: fused MFMA attention (R14 structure). CHANGE vs R14: dual
// sub-histograms split by lane parity, 128 bins: hist[row][2][129].
// Even lanes update copy 0, odd lanes copy 1 -> halves atomic bank
// serialization; scan sums both copies (2 bins/lane).
// ---------------------------------------------------------------------------
__global__ __launch_bounds__(512, 6) void attn_fused8_kernel(
    const u16* __restrict__ Qt, const u16* __restrict__ Kt,
    const u16* __restrict__ Vb, u16* __restrict__ aoutT)
{
    __shared__ u32 hist[16][2][129];   // 16512 B; aliased as red f32[8][32][16]
    __shared__ u32 candK[16][64];      // 4 KB
    __shared__ u32 candM[16][64];      // 4 KB
    __shared__ u16 Pst[8][16][40];     // 10 KB per-wave P staging
    __shared__ u32 kminA[16], maxkA[16], shA[16], kloA[16], khiA[16],
                   remKA[16], stateA[16], TkeyA[16], candCnt[16];
    __shared__ int cutA[16];
    __shared__ float denomF[16];
    __shared__ u32 flagS;

    int tid = threadIdx.x;
    int lane = tid & 63;
    int w = tid >> 6;            // wave 0..7
    int q = lane >> 4;           // quarter 0..3
    int cI = lane & 15;
    int par = lane & 1;          // sub-histogram selector
    int h = blockIdx.x / 144;
    int n0 = (blockIdx.x % 144) * 16;

    for (int i = tid; i < 16 * 2 * 129; i += 512) ((u32*)hist)[i] = 0u;
    if (tid < 16) {
        kminA[tid] = 0xFFFFFFFFu; maxkA[tid] = 0u; candCnt[tid] = 0u;
        denomF[tid] = 0.f; stateA[tid] = 0u; cutA[tid] = NN - 1;
        remKA[tid] = TOPK; TkeyA[tid] = 0u;
    }
    __syncthreads();

    const u16* Qth = Qt + (size_t)h * NN * CHD;
    const u16* Kth = Kt + (size_t)h * NN * CHD;
    const u16* Vbh = Vb + (size_t)h * CHD * NN;

    bf16x8 afrag = *(const bf16x8*)(Qth + (size_t)(n0 + cI) * CHD + q * 8);
    int mW = w * 288;
    const f32x4 zz = {0.f, 0.f, 0.f, 0.f};

    // ---- P0: exact per-row key min/max (shuffle-only reduce) ----
    {
        u32 lmin[4], lmax[4];
        #pragma unroll
        for (int r = 0; r < 4; ++r) { lmin[r] = 0xFFFFFFFFu; lmax[r] = 0u; }
        #pragma unroll 2
        for (int t = 0; t < 18; ++t) {
            bf16x8 bfrag = *(const bf16x8*)(Kth + (size_t)(mW + t * 16 + cI) * CHD + q * 8);
            f32x4 a = __builtin_amdgcn_mfma_f32_16x16x32_bf16(afrag, bfrag, zz, 0, 0, 0);
            #pragma unroll
            for (int r = 0; r < 4; ++r) {
                u32 k = fkey(a[r]);
                lmin[r] = min(lmin[r], k); lmax[r] = max(lmax[r], k);
            }
        }
        #pragma unroll
        for (int r = 0; r < 4; ++r) {
            #pragma unroll
            for (int mk = 1; mk < 16; mk <<= 1) {
                lmin[r] = min(lmin[r], (u32)__shfl_xor((int)lmin[r], mk));
                lmax[r] = max(lmax[r], (u32)__shfl_xor((int)lmax[r], mk));
            }
            if (cI == 0) {
                atomicMin(&kminA[4 * q + r], lmin[r]);
                atomicMax(&maxkA[4 * q + r], lmax[r]);
            }
        }
    }
    __syncthreads();
    if (tid < 16) shA[tid] = shiftOf128(maxkA[tid] - kminA[tid]);
    __syncthreads();

    // ---- P1: adaptive 128-bin histogram, dual parity copies ----
    {
        u32 km[4], sh[4];
        #pragma unroll
        for (int r = 0; r < 4; ++r) { km[r] = kminA[4 * q + r]; sh[r] = shA[4 * q + r]; }
        #pragma unroll 2
        for (int t = 0; t < 18; ++t) {
            bf16x8 bfrag = *(const bf16x8*)(Kth + (size_t)(mW + t * 16 + cI) * CHD + q * 8);
            f32x4 a = __builtin_amdgcn_mfma_f32_16x16x32_bf16(afrag, bfrag, zz, 0, 0, 0);
            #pragma unroll
            for (int r = 0; r < 4; ++r) {
                u32 k = fkey(a[r]);
                atomicAdd(&hist[4 * q + r][par][(k - km[r]) >> sh[r]], 1u);
            }
        }
    }
    __syncthreads();

    // ---- initial scan: per wave rows 2w, 2w+1 (2 bins/lane, 128 bins) ----
    #pragma unroll
    for (int rr = 0; rr < 2; ++rr) {
        int r = 2 * w + rr;
        u32 c0 = hist[r][0][lane * 2 + 0] + hist[r][1][lane * 2 + 0];
        u32 c1 = hist[r][0][lane * 2 + 1] + hist[r][1][lane * 2 + 1];
        u32 s1 = c1, s0 = c0 + c1;
        u32 suf = s0;
        #pragma unroll
        for (int off = 1; off < 64; off <<= 1) {
            u32 t2 = (u32)__shfl_down((int)suf, off);
            if (lane + off < 64) suf += t2;
        }
        u32 above_lane = suf - s0;
        u32 sArr[2] = {s0, s1};
        u32 cArr[2] = {c0, c1};
        u32 km = kminA[r], sh = shA[r];
        #pragma unroll
        for (int i = 0; i < 2; ++i) {
            u32 S = above_lane + sArr[i];
            u32 cb = cArr[i];
            if (S >= TOPK && S - cb < TOPK) {
                u32 b = lane * 2 + i;
                u32 klo = km + (b << sh);
                u64 khiL = (u64)km + ((u64)(b + 1) << sh) - 1ull;
                u32 khi = (khiL > 0xFFFFFFFFull) ? 0xFFFFFFFFu : (u32)khiL;
                kloA[r] = klo; khiA[r] = khi;
                remKA[r] = TOPK - (S - cb);
                if (cb <= 64u) stateA[r] = 1u;
                else if (klo == khi) { stateA[r] = 3u; TkeyA[r] = klo; }
                else stateA[r] = 0u;
            }
        }
    }
    __syncthreads();

    // ---- narrowing rounds (rare) ----
    for (int round = 0; round < 4; ++round) {
        if (tid == 0) {
            u32 any = 0;
            for (int r = 0; r < 16; ++r) any |= (stateA[r] == 0u) ? 1u : 0u;
            flagS = any;
        }
        __syncthreads();
        if (!flagS) break;
        if (tid < 258) {
            for (int r = 0; r < 16; ++r)
                if (stateA[r] == 0u) ((u32*)hist[r])[tid] = 0u;
        }
        __syncthreads();
        {
            u32 st2[4], kl2[4], sh2[4], kh2[4];
            #pragma unroll
            for (int r = 0; r < 4; ++r) {
                int row = 4 * q + r;
                st2[r] = stateA[row]; kl2[r] = kloA[row]; kh2[r] = khiA[row];
                sh2[r] = shiftOf128(kh2[r] - kl2[r]);
            }
            #pragma unroll 2
            for (int t = 0; t < 18; ++t) {
                bf16x8 bfrag = *(const bf16x8*)(Kth + (size_t)(mW + t * 16 + cI) * CHD + q * 8);
                f32x4 a = __builtin_amdgcn_mfma_f32_16x16x32_bf16(afrag, bfrag, zz, 0, 0, 0);
                #pragma unroll
                for (int r = 0; r < 4; ++r) {
                    if (st2[r] == 0u) {
                        u32 k = fkey(a[r]);
                        if (k >= kl2[r] && k <= kh2[r])
                            atomicAdd(&hist[4 * q + r][par][(k - kl2[r]) >> sh2[r]], 1u);
                    }
                }
            }
        }
        __syncthreads();
        #pragma unroll
        for (int rr = 0; rr < 2; ++rr) {
            int r = 2 * w + rr;
            if (stateA[r] != 0u) continue;
            u32 klo = kloA[r], khi = khiA[r];
            u32 sh = shiftOf128(khi - klo);
            u32 c0 = hist[r][0][lane * 2 + 0] + hist[r][1][lane * 2 + 0];
            u32 c1 = hist[r][0][lane * 2 + 1] + hist[r][1][lane * 2 + 1];
            u32 s1 = c1, s0 = c0 + c1;
            u32 suf = s0;
            #pragma unroll
            for (int off = 1; off < 64; off <<= 1) {
                u32 t2 = (u32)__shfl_down((int)suf, off);
                if (lane + off < 64) suf += t2;
            }
            u32 above_lane = suf - s0;
            u32 remK = remKA[r];
            u32 sArr[2] = {s0, s1};
            u32 cArr[2] = {c0, c1};
            #pragma unroll
            for (int i = 0; i < 2; ++i) {
                u32 S = above_lane + sArr[i];
                u32 cb = cArr[i];
                if (S >= remK && S - cb < remK) {
                    u32 b = lane * 2 + i;
                    u32 nlo = klo + (b << sh);
                    u64 nhiL = (u64)klo + ((u64)(b + 1) << sh) - 1ull;
                    u32 nhi = (nhiL > (u64)khi) ? khi : (u32)nhiL;
                    kloA[r] = nlo; khiA[r] = nhi;
                    remKA[r] = remK - (S - cb);
                    if (cb <= 64u) stateA[r] = 1u;
                    else if (nlo == nhi) { stateA[r] = 3u; TkeyA[r] = nlo; }
                    else stateA[r] = 0u;
                }
            }
        }
        __syncthreads();
    }
    if (tid < 16 && stateA[tid] == 0u) {   // unreachable safety
        TkeyA[tid] = kloA[tid]; stateA[tid] = 3u;
    }
    __syncthreads();

    // ---- P2: candidate collection ----
    {
        u32 st[4], kl[4], kh[4];
        #pragma unroll
        for (int r = 0; r < 4; ++r) {
            int row = 4 * q + r;
            st[r] = stateA[row]; kl[r] = kloA[row]; kh[r] = khiA[row];
        }
        #pragma unroll 2
        for (int t = 0; t < 18; ++t) {
            bf16x8 bfrag = *(const bf16x8*)(Kth + (size_t)(mW + t * 16 + cI) * CHD + q * 8);
            f32x4 a = __builtin_amdgcn_mfma_f32_16x16x32_bf16(afrag, bfrag, zz, 0, 0, 0);
            int m = mW + t * 16 + cI;
            #pragma unroll
            for (int r = 0; r < 4; ++r) {
                if (st[r] == 1u) {
                    u32 k = fkey(a[r]);
                    if (k >= kl[r] && k <= kh[r]) {
                        int row = 4 * q + r;
                        u32 pos = atomicAdd(&candCnt[row], 1u);
                        if (pos < 64u) { candK[row][pos] = k; candM[row][pos] = (u32)m; }
                    }
                }
            }
        }
    }
    __syncthreads();

    // ---- resolve: rank remK-th by (key desc, index asc) -> T, cut ----
    #pragma unroll
    for (int rr = 0; rr < 2; ++rr) {
        int r = 2 * w + rr;
        if (stateA[r] == 1u) {
            u32 cnt = min(candCnt[r], 64u);
            u32 remK = remKA[r];
            u32 myk = 0u, mym = 0u;
            if (lane < (int)cnt) { myk = candK[r][lane]; mym = candM[r][lane]; }
            u32 gtr = 0;
            for (u32 i = 0; i < cnt; ++i) {
                u32 ki = candK[r][i], mi = candM[r][i];
                gtr += (ki > myk || (ki == myk && mi < mym)) ? 1u : 0u;
            }
            if (lane < (int)cnt && gtr == remK - 1u) {
                TkeyA[r] = myk; cutA[r] = (int)mym;
            }
        }
    }
    __syncthreads();

    // ---- P3: recompute -> masked exp -> P bf16 -> PV MFMA ----
    {
        float maxf[4], ls[4];
        u32 Tr[4]; int cutr[4];
        #pragma unroll
        for (int r = 0; r < 4; ++r) {
            int row = 4 * q + r;
            maxf[r] = fkey_inv(maxkA[row]);
            Tr[r] = TkeyA[row];
            cutr[r] = cutA[row];
            ls[r] = 0.f;
        }
        f32x4 acc0 = {0.f, 0.f, 0.f, 0.f};
        f32x4 acc1 = {0.f, 0.f, 0.f, 0.f};
        for (int j = 0; j < 9; ++j) {
            int mb = mW + j * 32;
            bf16x8 b0 = *(const bf16x8*)(Kth + (size_t)(mb + cI) * CHD + q * 8);
            bf16x8 b1 = *(const bf16x8*)(Kth + (size_t)(mb + 16 + cI) * CHD + q * 8);
            f32x4 a0 = __builtin_amdgcn_mfma_f32_16x16x32_bf16(afrag, b0, zz, 0, 0, 0);
            f32x4 a1 = __builtin_amdgcn_mfma_f32_16x16x32_bf16(afrag, b1, zz, 0, 0, 0);
            #pragma unroll
            for (int r = 0; r < 4; ++r) {
                {
                    float s = a0[r];
                    u32 k = fkey(s);
                    int m = mb + cI;
                    bool inc = (k > Tr[r]) || (k == Tr[r] && m <= cutr[r]);
                    float p = inc ? __expf(s - maxf[r]) : 0.f;
                    ls[r] += p;
                    Pst[w][4 * q + r][cI] = f2bf(p);
                }
                {
                    float s = a1[r];
                    u32 k = fkey(s);
                    int m = mb + 16 + cI;
                    bool inc = (k > Tr[r]) || (k == Tr[r] && m <= cutr[r]);
                    float p = inc ? __expf(s - maxf[r]) : 0.f;
                    ls[r] += p;
                    Pst[w][4 * q + r][16 + cI] = f2bf(p);
                }
            }
            bf16x8 pf = *(const bf16x8*)&Pst[w][cI][q * 8];
            bf16x8 v0 = *(const bf16x8*)(Vbh + (size_t)cI * NN + mb + q * 8);
            bf16x8 v1 = *(const bf16x8*)(Vbh + (size_t)(16 + cI) * NN + mb + q * 8);
            acc0 = __builtin_amdgcn_mfma_f32_16x16x32_bf16(v0, pf, acc0, 0, 0, 0);
            acc1 = __builtin_amdgcn_mfma_f32_16x16x32_bf16(v1, pf, acc1, 0, 0, 0);
        }
        #pragma unroll
        for (int r = 0; r < 4; ++r) {
            #pragma unroll
            for (int mk = 1; mk < 16; mk <<= 1)
                ls[r] += __shfl_xor(ls[r], mk);
            if (cI == 0) atomicAdd(&denomF[4 * q + r], ls[r]);
        }
        __syncthreads();              // hist dead -> red alias safe
        float* red = (float*)hist;    // [8][32][16]
        #pragma unroll
        for (int r = 0; r < 4; ++r) {
            red[((size_t)w * 32 + (4 * q + r)) * 16 + cI] = acc0[r];
            red[((size_t)w * 32 + 16 + (4 * q + r)) * 16 + cI] = acc1[r];
        }
    }
    __syncthreads();

    // ---- epilogue: cross-wave reduce, normalize, store bf16 aout^T ----
    {
        const float* red = (const float*)hist;
        int c = tid >> 4, n = tid & 15;
        float s = 0.f;
        #pragma unroll
        for (int w2 = 0; w2 < 8; ++w2) s += red[((size_t)w2 * 32 + c) * 16 + n];
        s /= denomF[n];
        int ng = n0 + n;
        int t = ng & 3, p = ng >> 2;
        aoutT[(size_t)p * DIM + t * CS + h * CHD + c] = f2bf(s);
    }
}

// ---------------------------------------------------------------------------
// Kernel 4: out = x + w_proj @ attn_out via bf16 MFMA.
// ---------------------------------------------------------------------------
__global__ __launch_bounds__(256) void proj_mfma_kernel(
    const u16* __restrict__ aoutT, const u16* __restrict__ wpb,
    const float* __restrict__ x, float* __restrict__ out)
{
    int tid = threadIdx.x, lane = tid & 63, w = tid >> 6;
    int q = lane >> 4, cI = lane & 15;
    int p0 = blockIdx.x * 16;
    int o0 = blockIdx.y * 64 + w * 16;
    f32x4 acc = {0.f, 0.f, 0.f, 0.f};
    const u16* arow = wpb + (size_t)(o0 + cI) * DIM + q * 8;
    const u16* brow = aoutT + (size_t)(p0 + cI) * DIM + q * 8;
    #pragma unroll 8
    for (int k = 0; k < DIM; k += 32) {
        bf16x8 af = *(const bf16x8*)(arow + k);
        bf16x8 bf = *(const bf16x8*)(brow + k);
        acc = __builtin_amdgcn_mfma_f32_16x16x32_bf16(af, bf, acc, 0, 0, 0);
    }
    #pragma unroll
    for (int r = 0; r < 4; ++r) {
        int o = o0 + 4 * q + r, p = p0 + cI;
        out[(size_t)o * HW + p] = x[(size_t)o * HW + p] + acc[r];
    }
}

// ---------------------------------------------------------------------------
extern "C" void kernel_launch(void* const* d_in, const int* in_sizes, int n_in,
                              void* d_out, int out_size, void* d_ws, size_t ws_size,
                              hipStream_t stream)
{
    const float* x     = (const float*)d_in[0];
    const float* temp  = (const float*)d_in[1];
    const float* w_qkv = (const float*)d_in[2];
    const float* w_dw  = (const float*)d_in[3];
    const float* wproj = (const float*)d_in[4];
    float* out = (float*)d_out;

    const size_t T = (size_t)NHEADS * CHD * NN;    // 589824
    char* ws = (char*)d_ws;
    float* qb    = (float*)(ws);                   // T f32
    float* kb    = (float*)(ws + 4 * T);           // T f32
    u16*   Qt    = (u16*)(ws + 8 * T);             // T bf16
    u16*   Kt    = (u16*)(ws + 10 * T);            // T bf16
    u16*   Vb    = (u16*)(ws + 12 * T);            // T bf16
    u16*   aoutT = (u16*)(ws + 14 * T);            // HW*DIM bf16 (= 2T bytes)
    u16*   wpb   = (u16*)(ws + 16 * T);            // DIM*DIM bf16 (2 MB)
    float* scales= (float*)(ws + 16 * T + (size_t)DIM * DIM * 2);  // 512 f32

    qkv_conv_kernel<<<256, 256, 0, stream>>>(x, w_qkv, w_dw, qb, kb, Vb, scales);
    transpose_cast_kernel<<<dim3(72, 8, 2), 256, 0, stream>>>(qb, kb, scales, temp, Qt, Kt);
    cast_wproj_kernel<<<DIM * DIM / 4 / 256, 256, 0, stream>>>(wproj, wpb);
    attn_fused8_kernel<<<NHEADS * 144, 512, 0, stream>>>(Qt, Kt, Vb, aoutT);
    proj_mfma_kernel<<<dim3(36, 16), 256, 0, stream>>>(aoutT, wpb, x, out);
}

// Round 16
// 148.339 us; speedup vs baseline: 1.0286x; 1.0286x over previous
//
#include <hip/hip_runtime.h>
#include <math.h>

typedef unsigned int u32;
typedef unsigned long long u64;
typedef unsigned short u16;
typedef __attribute__((ext_vector_type(8))) short bf16x8;
typedef __attribute__((ext_vector_type(4))) float f32x4;

#define NHEADS 8
#define HH 24
#define WW 24
#define HW 576
#define CS 256        // channels per group
#define CHD 32        // channels per head
#define NN 2304       // HW * NGROUPS
#define NGROUPS 4
#define TOPK 1843     // int(2304 * 0.8)
#define DIM 1024
#define EPSN 1e-12f

__device__ __forceinline__ u32 fkey(float f) {
    u32 u = __float_as_uint(f);
    return u ^ ((u >> 31) ? 0xFFFFFFFFu : 0x80000000u);  // monotonic map
}
__device__ __forceinline__ float fkey_inv(u32 k) {
    return __uint_as_float((k & 0x80000000u) ? (k ^ 0x80000000u) : ~k);
}
__device__ __forceinline__ u16 f2bf(float f) {          // RNE fp32->bf16
    u32 u = __float_as_uint(f);
    return (u16)((u + 0x7FFFu + ((u >> 16) & 1u)) >> 16);
}
__device__ __forceinline__ u32 shiftOf(u32 rg) {        // 256-bin shift
    return (rg > 255u) ? (u32)(24 - __clz(rg)) : 0u;
}

// ---------------------------------------------------------------------------
// Kernel 1: fused group-mix (w_qkv) + depthwise 3x3 conv + q/k norm reduce.
// Block c owns channel c's ENTIRE q/k rows -> computes scales in-kernel.
// ---------------------------------------------------------------------------
__global__ __launch_bounds__(256) void qkv_conv_kernel(
    const float* __restrict__ x, const float* __restrict__ w_qkv,
    const float* __restrict__ w_dw,
    float* __restrict__ qb, float* __restrict__ kb, u16* __restrict__ vb16,
    float* __restrict__ scales)
{
    __shared__ float xp[NGROUPS][26][26];
    __shared__ float wq[48];
    __shared__ float wd[108];
    __shared__ float redq[4], redk[4];
    int c = blockIdx.x;          // 0..255
    int tid = threadIdx.x;
    int lane = tid & 63, wid = tid >> 6;

    for (int i = tid; i < NGROUPS * 26 * 26; i += 256) ((float*)xp)[i] = 0.f;
    if (tid < 48) wq[tid] = w_qkv[tid];
    if (tid < 108) wd[tid] = w_dw[tid];
    __syncthreads();
    for (int i = tid; i < NGROUPS * HW; i += 256) {
        int t = i / HW, p = i % HW;
        int hh = p / WW, ww = p % WW;
        xp[t][hh + 1][ww + 1] = x[(size_t)(t * CS + c) * HW + p];
    }
    __syncthreads();

    int hd = c >> 5, ch = c & 31;
    float ssq = 0.f, ssk = 0.f;
    for (int p = tid; p < HW; p += 256) {
        int hh = p / WW, ww = p % WW;
        float res[12];
        #pragma unroll
        for (int s = 0; s < 12; ++s) {
            float acc = 0.f;
            #pragma unroll
            for (int t = 0; t < NGROUPS; ++t) {
                float cv = 0.f;
                #pragma unroll
                for (int dh = 0; dh < 3; ++dh)
                    #pragma unroll
                    for (int dw = 0; dw < 3; ++dw)
                        cv += xp[t][hh + dh][ww + dw] * wd[s * 9 + dh * 3 + dw];
                acc += wq[s * 4 + t] * cv;
            }
            res[s] = acc;
        }
        #pragma unroll
        for (int tt = 0; tt < 4; ++tt) {
            int n = p * 4 + tt;
            size_t off = ((size_t)hd * CHD + ch) * NN + n;
            qb[off] = res[tt];
            kb[off] = res[4 + tt];
            vb16[off] = f2bf(res[8 + tt]);
            ssq += res[tt] * res[tt];
            ssk += res[4 + tt] * res[4 + tt];
        }
    }
    #pragma unroll
    for (int off = 32; off > 0; off >>= 1) {
        ssq += __shfl_down(ssq, off);
        ssk += __shfl_down(ssk, off);
    }
    if (lane == 0) { redq[wid] = ssq; redk[wid] = ssk; }
    __syncthreads();
    if (tid == 0) {
        float sq = redq[0] + redq[1] + redq[2] + redq[3];
        float sk = redk[0] + redk[1] + redk[2] + redk[3];
        scales[c] = 1.f / fmaxf(sqrtf(sq), EPSN);
        scales[256 + c] = 1.f / fmaxf(sqrtf(sk), EPSN);
    }
}

// ---------------------------------------------------------------------------
// Kernel 2b: transpose+scale+cast q,k: [h][c][n] fp32 -> [h][n][c] bf16
// Temperature folded into Qt.
// ---------------------------------------------------------------------------
__global__ __launch_bounds__(256) void transpose_cast_kernel(
    const float* __restrict__ qb, const float* __restrict__ kb,
    const float* __restrict__ scales, const float* __restrict__ temp,
    u16* __restrict__ Qt, u16* __restrict__ Kt)
{
    __shared__ float tile[32][33];
    int ntile = blockIdx.x;        // 0..71
    int h = blockIdx.y;            // 0..7
    int which = blockIdx.z;        // 0=q 1=k
    const float* src = which ? kb : qb;
    const float* scl = scales + which * 256;
    u16* dst = which ? Kt : Qt;
    float tf = which ? 1.f : temp[h];
    int tid = threadIdx.x;
    int n0 = ntile * 32;
    #pragma unroll
    for (int cc = 0; cc < 32; cc += 8) {
        int c = cc + (tid >> 5);
        tile[c][tid & 31] = src[(size_t)(h * CHD + c) * NN + n0 + (tid & 31)]
                            * scl[h * CHD + c] * tf;
    }
    __syncthreads();
    int cgrp = tid & 7, nrow = tid >> 3;
    #pragma unroll
    for (int c0 = 0; c0 < 32; c0 += 16) {
        int c = c0 + cgrp * 2;
        u16 v0 = f2bf(tile[c][nrow]);
        u16 v1 = f2bf(tile[c + 1][nrow]);
        ushort2 v; v.x = v0; v.y = v1;
        *(ushort2*)(dst + ((size_t)h * NN + n0 + nrow) * CHD + c) = v;
    }
}

// ---------------------------------------------------------------------------
// Kernel 2c: cast w_proj fp32 -> bf16
// ---------------------------------------------------------------------------
__global__ __launch_bounds__(256) void cast_wproj_kernel(
    const float* __restrict__ wp, u16* __restrict__ wpb)
{
    int i = blockIdx.x * 256 + threadIdx.x;   // DIM*DIM/4 elems of float4
    float4 v = ((const float4*)wp)[i];
    ushort4 o;
    o.x = f2bf(v.x); o.y = f2bf(v.y); o.z = f2bf(v.z); o.w = f2bf(v.w);
    ((ushort4*)wpb)[i] = o;
}

// ---------------------------------------------------------------------------
// Kernel 3: fused MFMA attention (R14 structure verbatim) + XCD-aware block
// swizzle: grid 1152 = 8 XCDs x 144; work = (bid&7)*144 + (bid>>3) gives each
// XCD all 144 tiles of ONE head -> head's Qt/Kt/V (~3.5 MB) is L2-resident
// across all 4 recompute passes.
// ---------------------------------------------------------------------------
__global__ __launch_bounds__(512, 6) void attn_fused9_kernel(
    const u16* __restrict__ Qt, const u16* __restrict__ Kt,
    const u16* __restrict__ Vb, u16* __restrict__ aoutT)
{
    __shared__ u32 hist[16][257];      // 16448 B; aliased as red f32[8][32][16]
    __shared__ u32 candK[16][64];      // 4 KB
    __shared__ u32 candM[16][64];      // 4 KB
    __shared__ u16 Pst[8][16][40];     // 10 KB per-wave P staging
    __shared__ u32 kminA[16], maxkA[16], shA[16], kloA[16], khiA[16],
                   remKA[16], stateA[16], TkeyA[16], candCnt[16];
    __shared__ int cutA[16];
    __shared__ float denomF[16];
    __shared__ u32 flagS;

    int tid = threadIdx.x;
    int lane = tid & 63;
    int w = tid >> 6;            // wave 0..7
    int q = lane >> 4;           // quarter 0..3
    int cI = lane & 15;
    int bid = blockIdx.x;
    int work = (bid & 7) * 144 + (bid >> 3);   // XCD-contiguous head chunks
    int h = work / 144;
    int n0 = (work % 144) * 16;

    for (int i = tid; i < 16 * 257; i += 512) ((u32*)hist)[i] = 0u;
    if (tid < 16) {
        kminA[tid] = 0xFFFFFFFFu; maxkA[tid] = 0u; candCnt[tid] = 0u;
        denomF[tid] = 0.f; stateA[tid] = 0u; cutA[tid] = NN - 1;
        remKA[tid] = TOPK; TkeyA[tid] = 0u;
    }
    __syncthreads();

    const u16* Qth = Qt + (size_t)h * NN * CHD;
    const u16* Kth = Kt + (size_t)h * NN * CHD;
    const u16* Vbh = Vb + (size_t)h * CHD * NN;

    bf16x8 afrag = *(const bf16x8*)(Qth + (size_t)(n0 + cI) * CHD + q * 8);
    int mW = w * 288;
    const f32x4 zz = {0.f, 0.f, 0.f, 0.f};

    // ---- P0: exact per-row key min/max (shuffle-only reduce) ----
    {
        u32 lmin[4], lmax[4];
        #pragma unroll
        for (int r = 0; r < 4; ++r) { lmin[r] = 0xFFFFFFFFu; lmax[r] = 0u; }
        #pragma unroll 2
        for (int t = 0; t < 18; ++t) {
            bf16x8 bfrag = *(const bf16x8*)(Kth + (size_t)(mW + t * 16 + cI) * CHD + q * 8);
            f32x4 a = __builtin_amdgcn_mfma_f32_16x16x32_bf16(afrag, bfrag, zz, 0, 0, 0);
            #pragma unroll
            for (int r = 0; r < 4; ++r) {
                u32 k = fkey(a[r]);
                lmin[r] = min(lmin[r], k); lmax[r] = max(lmax[r], k);
            }
        }
        #pragma unroll
        for (int r = 0; r < 4; ++r) {
            #pragma unroll
            for (int mk = 1; mk < 16; mk <<= 1) {
                lmin[r] = min(lmin[r], (u32)__shfl_xor((int)lmin[r], mk));
                lmax[r] = max(lmax[r], (u32)__shfl_xor((int)lmax[r], mk));
            }
            if (cI == 0) {
                atomicMin(&kminA[4 * q + r], lmin[r]);
                atomicMax(&maxkA[4 * q + r], lmax[r]);
            }
        }
    }
    __syncthreads();
    if (tid < 16) shA[tid] = shiftOf(maxkA[tid] - kminA[tid]);
    __syncthreads();

    // ---- P1: adaptive histogram (bank-spread [row][257]) ----
    {
        u32 km[4], sh[4];
        #pragma unroll
        for (int r = 0; r < 4; ++r) { km[r] = kminA[4 * q + r]; sh[r] = shA[4 * q + r]; }
        #pragma unroll 2
        for (int t = 0; t < 18; ++t) {
            bf16x8 bfrag = *(const bf16x8*)(Kth + (size_t)(mW + t * 16 + cI) * CHD + q * 8);
            f32x4 a = __builtin_amdgcn_mfma_f32_16x16x32_bf16(afrag, bfrag, zz, 0, 0, 0);
            #pragma unroll
            for (int r = 0; r < 4; ++r) {
                u32 k = fkey(a[r]);
                atomicAdd(&hist[4 * q + r][(k - km[r]) >> sh[r]], 1u);
            }
        }
    }
    __syncthreads();

    // ---- initial scan: per wave rows 2w, 2w+1 (4 bins/lane, 256 bins) ----
    #pragma unroll
    for (int rr = 0; rr < 2; ++rr) {
        int r = 2 * w + rr;
        u32 c0 = hist[r][lane * 4 + 0];
        u32 c1 = hist[r][lane * 4 + 1];
        u32 c2 = hist[r][lane * 4 + 2];
        u32 c3 = hist[r][lane * 4 + 3];
        u32 s3 = c3, s2 = c2 + s3, s1 = c1 + s2, s0 = c0 + s1;
        u32 suf = s0;
        #pragma unroll
        for (int off = 1; off < 64; off <<= 1) {
            u32 t2 = (u32)__shfl_down((int)suf, off);
            if (lane + off < 64) suf += t2;
        }
        u32 above_lane = suf - s0;
        u32 sArr[4] = {s0, s1, s2, s3};
        u32 cArr[4] = {c0, c1, c2, c3};
        u32 km = kminA[r], sh = shA[r];
        #pragma unroll
        for (int i = 0; i < 4; ++i) {
            u32 S = above_lane + sArr[i];
            u32 cb = cArr[i];
            if (S >= TOPK && S - cb < TOPK) {
                u32 b = lane * 4 + i;
                u32 klo = km + (b << sh);
                u64 khiL = (u64)km + ((u64)(b + 1) << sh) - 1ull;
                u32 khi = (khiL > 0xFFFFFFFFull) ? 0xFFFFFFFFu : (u32)khiL;
                kloA[r] = klo; khiA[r] = khi;
                remKA[r] = TOPK - (S - cb);
                if (cb <= 64u) stateA[r] = 1u;
                else if (klo == khi) { stateA[r] = 3u; TkeyA[r] = klo; }
                else stateA[r] = 0u;
            }
        }
    }
    __syncthreads();

    // ---- narrowing rounds (rare) ----
    for (int round = 0; round < 4; ++round) {
        if (tid == 0) {
            u32 any = 0;
            for (int r = 0; r < 16; ++r) any |= (stateA[r] == 0u) ? 1u : 0u;
            flagS = any;
        }
        __syncthreads();
        if (!flagS) break;
        if (tid < 257) {
            for (int r = 0; r < 16; ++r)
                if (stateA[r] == 0u) hist[r][tid] = 0u;
        }
        __syncthreads();
        {
            u32 st2[4], kl2[4], sh2[4], kh2[4];
            #pragma unroll
            for (int r = 0; r < 4; ++r) {
                int row = 4 * q + r;
                st2[r] = stateA[row]; kl2[r] = kloA[row]; kh2[r] = khiA[row];
                sh2[r] = shiftOf(kh2[r] - kl2[r]);
            }
            #pragma unroll 2
            for (int t = 0; t < 18; ++t) {
                bf16x8 bfrag = *(const bf16x8*)(Kth + (size_t)(mW + t * 16 + cI) * CHD + q * 8);
                f32x4 a = __builtin_amdgcn_mfma_f32_16x16x32_bf16(afrag, bfrag, zz, 0, 0, 0);
                #pragma unroll
                for (int r = 0; r < 4; ++r) {
                    if (st2[r] == 0u) {
                        u32 k = fkey(a[r]);
                        if (k >= kl2[r] && k <= kh2[r])
                            atomicAdd(&hist[4 * q + r][(k - kl2[r]) >> sh2[r]], 1u);
                    }
                }
            }
        }
        __syncthreads();
        #pragma unroll
        for (int rr = 0; rr < 2; ++rr) {
            int r = 2 * w + rr;
            if (stateA[r] != 0u) continue;
            u32 klo = kloA[r], khi = khiA[r];
            u32 sh = shiftOf(khi - klo);
            u32 c0 = hist[r][lane * 4 + 0];
            u32 c1 = hist[r][lane * 4 + 1];
            u32 c2 = hist[r][lane * 4 + 2];
            u32 c3 = hist[r][lane * 4 + 3];
            u32 s3 = c3, s2 = c2 + s3, s1 = c1 + s2, s0 = c0 + s1;
            u32 suf = s0;
            #pragma unroll
            for (int off = 1; off < 64; off <<= 1) {
                u32 t2 = (u32)__shfl_down((int)suf, off);
                if (lane + off < 64) suf += t2;
            }
            u32 above_lane = suf - s0;
            u32 remK = remKA[r];
            u32 sArr[4] = {s0, s1, s2, s3};
            u32 cArr[4] = {c0, c1, c2, c3};
            #pragma unroll
            for (int i = 0; i < 4; ++i) {
                u32 S = above_lane + sArr[i];
                u32 cb = cArr[i];
                if (S >= remK && S - cb < remK) {
                    u32 b = lane * 4 + i;
                    u32 nlo = klo + (b << sh);
                    u64 nhiL = (u64)klo + ((u64)(b + 1) << sh) - 1ull;
                    u32 nhi = (nhiL > (u64)khi) ? khi : (u32)nhiL;
                    kloA[r] = nlo; khiA[r] = nhi;
                    remKA[r] = remK - (S - cb);
                    if (cb <= 64u) stateA[r] = 1u;
                    else if (nlo == nhi) { stateA[r] = 3u; TkeyA[r] = nlo; }
                    else stateA[r] = 0u;
                }
            }
        }
        __syncthreads();
    }
    if (tid < 16 && stateA[tid] == 0u) {   // unreachable safety
        TkeyA[tid] = kloA[tid]; stateA[tid] = 3u;
    }
    __syncthreads();

    // ---- P2: candidate collection ----
    {
        u32 st[4], kl[4], kh[4];
        #pragma unroll
        for (int r = 0; r < 4; ++r) {
            int row = 4 * q + r;
            st[r] = stateA[row]; kl[r] = kloA[row]; kh[r] = khiA[row];
        }
        #pragma unroll 2
        for (int t = 0; t < 18; ++t) {
            bf16x8 bfrag = *(const bf16x8*)(Kth + (size_t)(mW + t * 16 + cI) * CHD + q * 8);
            f32x4 a = __builtin_amdgcn_mfma_f32_16x16x32_bf16(afrag, bfrag, zz, 0, 0, 0);
            int m = mW + t * 16 + cI;
            #pragma unroll
            for (int r = 0; r < 4; ++r) {
                if (st[r] == 1u) {
                    u32 k = fkey(a[r]);
                    if (k >= kl[r] && k <= kh[r]) {
                        int row = 4 * q + r;
                        u32 pos = atomicAdd(&candCnt[row], 1u);
                        if (pos < 64u) { candK[row][pos] = k; candM[row][pos] = (u32)m; }
                    }
                }
            }
        }
    }
    __syncthreads();

    // ---- resolve: rank remK-th by (key desc, index asc) -> T, cut ----
    #pragma unroll
    for (int rr = 0; rr < 2; ++rr) {
        int r = 2 * w + rr;
        if (stateA[r] == 1u) {
            u32 cnt = min(candCnt[r], 64u);
            u32 remK = remKA[r];
            u32 myk = 0u, mym = 0u;
            if (lane < (int)cnt) { myk = candK[r][lane]; mym = candM[r][lane]; }
            u32 gtr = 0;
            for (u32 i = 0; i < cnt; ++i) {
                u32 ki = candK[r][i], mi = candM[r][i];
                gtr += (ki > myk || (ki == myk && mi < mym)) ? 1u : 0u;
            }
            if (lane < (int)cnt && gtr == remK - 1u) {
                TkeyA[r] = myk; cutA[r] = (int)mym;
            }
        }
    }
    __syncthreads();

    // ---- P3: recompute -> masked exp -> P bf16 -> PV MFMA ----
    {
        float maxf[4], ls[4];
        u32 Tr[4]; int cutr[4];
        #pragma unroll
        for (int r = 0; r < 4; ++r) {
            int row = 4 * q + r;
            maxf[r] = fkey_inv(maxkA[row]);
            Tr[r] = TkeyA[row];
            cutr[r] = cutA[row];
            ls[r] = 0.f;
        }
        f32x4 acc0 = {0.f, 0.f, 0.f, 0.f};
        f32x4 acc1 = {0.f, 0.f, 0.f, 0.f};
        for (int j = 0; j < 9; ++j) {
            int mb = mW + j * 32;
            bf16x8 b0 = *(const bf16x8*)(Kth + (size_t)(mb + cI) * CHD + q * 8);
            bf16x8 b1 = *(const bf16x8*)(Kth + (size_t)(mb + 16 + cI) * CHD + q * 8);
            f32x4 a0 = __builtin_amdgcn_mfma_f32_16x16x32_bf16(afrag, b0, zz, 0, 0, 0);
            f32x4 a1 = __builtin_amdgcn_mfma_f32_16x16x32_bf16(afrag, b1, zz, 0, 0, 0);
            #pragma unroll
            for (int r = 0; r < 4; ++r) {
                {
                    float s = a0[r];
                    u32 k = fkey(s);
                    int m = mb + cI;
                    bool inc = (k > Tr[r]) || (k == Tr[r] && m <= cutr[r]);
                    float p = inc ? __expf(s - maxf[r]) : 0.f;
                    ls[r] += p;
                    Pst[w][4 * q + r][cI] = f2bf(p);
                }
                {
                    float s = a1[r];
                    u32 k = fkey(s);
                    int m = mb + 16 + cI;
                    bool inc = (k > Tr[r]) || (k == Tr[r] && m <= cutr[r]);
                    float p = inc ? __expf(s - maxf[r]) : 0.f;
                    ls[r] += p;
                    Pst[w][4 * q + r][16 + cI] = f2bf(p);
                }
            }
            bf16x8 pf = *(const bf16x8*)&Pst[w][cI][q * 8];
            bf16x8 v0 = *(const bf16x8*)(Vbh + (size_t)cI * NN + mb + q * 8);
            bf16x8 v1 = *(const bf16x8*)(Vbh + (size_t)(16 + cI) * NN + mb + q * 8);
            acc0 = __builtin_amdgcn_mfma_f32_16x16x32_bf16(v0, pf, acc0, 0, 0, 0);
            acc1 = __builtin_amdgcn_mfma_f32_16x16x32_bf16(v1, pf, acc1, 0, 0, 0);
        }
        #pragma unroll
        for (int r = 0; r < 4; ++r) {
            #pragma unroll
            for (int mk = 1; mk < 16; mk <<= 1)
                ls[r] += __shfl_xor(ls[r], mk);
            if (cI == 0) atomicAdd(&denomF[4 * q + r], ls[r]);
        }
        __syncthreads();              // hist dead -> red alias safe
        float* red = (float*)hist;    // [8][32][16]
        #pragma unroll
        for (int r = 0; r < 4; ++r) {
            red[((size_t)w * 32 + (4 * q + r)) * 16 + cI] = acc0[r];
            red[((size_t)w * 32 + 16 + (4 * q + r)) * 16 + cI] = acc1[r];
        }
    }
    __syncthreads();

    // ---- epilogue: cross-wave reduce, normalize, store bf16 aout^T ----
    {
        const float* red = (const float*)hist;
        int c = tid >> 4, n = tid & 15;
        float s = 0.f;
        #pragma unroll
        for (int w2 = 0; w2 < 8; ++w2) s += red[((size_t)w2 * 32 + c) * 16 + n];
        s /= denomF[n];
        int ng = n0 + n;
        int t = ng & 3, p = ng >> 2;
        aoutT[(size_t)p * DIM + t * CS + h * CHD + c] = f2bf(s);
    }
}

// ---------------------------------------------------------------------------
// Kernel 4: out = x + w_proj @ attn_out via bf16 MFMA.
// ---------------------------------------------------------------------------
__global__ __launch_bounds__(256) void proj_mfma_kernel(
    const u16* __restrict__ aoutT, const u16* __restrict__ wpb,
    const float* __restrict__ x, float* __restrict__ out)
{
    int tid = threadIdx.x, lane = tid & 63, w = tid >> 6;
    int q = lane >> 4, cI = lane & 15;
    int p0 = blockIdx.x * 16;
    int o0 = blockIdx.y * 64 + w * 16;
    f32x4 acc = {0.f, 0.f, 0.f, 0.f};
    const u16* arow = wpb + (size_t)(o0 + cI) * DIM + q * 8;
    const u16* brow = aoutT + (size_t)(p0 + cI) * DIM + q * 8;
    #pragma unroll 8
    for (int k = 0; k < DIM; k += 32) {
        bf16x8 af = *(const bf16x8*)(arow + k);
        bf16x8 bf = *(const bf16x8*)(brow + k);
        acc = __builtin_amdgcn_mfma_f32_16x16x32_bf16(af, bf, acc, 0, 0, 0);
    }
    #pragma unroll
    for (int r = 0; r < 4; ++r) {
        int o = o0 + 4 * q + r, p = p0 + cI;
        out[(size_t)o * HW + p] = x[(size_t)o * HW + p] + acc[r];
    }
}

// ---------------------------------------------------------------------------
extern "C" void kernel_launch(void* const* d_in, const int* in_sizes, int n_in,
                              void* d_out, int out_size, void* d_ws, size_t ws_size,
                              hipStream_t stream)
{
    const float* x     = (const float*)d_in[0];
    const float* temp  = (const float*)d_in[1];
    const float* w_qkv = (const float*)d_in[2];
    const float* w_dw  = (const float*)d_in[3];
    const float* wproj = (const float*)d_in[4];
    float* out = (float*)d_out;

    const size_t T = (size_t)NHEADS * CHD * NN;    // 589824
    char* ws = (char*)d_ws;
    float* qb    = (float*)(ws);                   // T f32
    float* kb    = (float*)(ws + 4 * T);           // T f32
    u16*   Qt    = (u16*)(ws + 8 * T);             // T bf16
    u16*   Kt    = (u16*)(ws + 10 * T);            // T bf16
    u16*   Vb    = (u16*)(ws + 12 * T);            // T bf16
    u16*   aoutT = (u16*)(ws + 14 * T);            // HW*DIM bf16 (= 2T bytes)
    u16*   wpb   = (u16*)(ws + 16 * T);            // DIM*DIM bf16 (2 MB)
    float* scales= (float*)(ws + 16 * T + (size_t)DIM * DIM * 2);  // 512 f32

    qkv_conv_kernel<<<256, 256, 0, stream>>>(x, w_qkv, w_dw, qb, kb, Vb, scales);
    transpose_cast_kernel<<<dim3(72, 8, 2), 256, 0, stream>>>(qb, kb, scales, temp, Qt, Kt);
    cast_wproj_kernel<<<DIM * DIM / 4 / 256, 256, 0, stream>>>(wproj, wpb);
    attn_fused9_kernel<<<NHEADS * 144, 512, 0, stream>>>(Qt, Kt, Vb, aoutT);
    proj_mfma_kernel<<<dim3(36, 16), 256, 0, stream>>>(aoutT, wpb, x, out);
}